// Round 1
// baseline (650.274 us; speedup 1.0000x reference)
//
#include <hip/hip_runtime.h>

// B=32, LV=196, LT=40, D=512, H=8, DH=64
// ws layout: ~60 MB of bf16 intermediates (see kernel_launch).

typedef unsigned int u32;
typedef unsigned short u16;
typedef __attribute__((ext_vector_type(8))) short bf16x8;
typedef __attribute__((ext_vector_type(4))) float f32x4;

#define DEV __device__ __forceinline__

DEV u16 f2bf(float f) {
  u32 u = __builtin_bit_cast(u32, f);
  u = (u + 0x7FFFu + ((u >> 16) & 1u)) >> 16;
  return (u16)u;
}
DEV float bf2f(u16 h) { u32 u = ((u32)h) << 16; return __builtin_bit_cast(float, u); }
// monotonic float<->u32 encoding for atomicMax on floats (enc(x)>enc(y) iff x>y)
DEV u32 encf(float f) { u32 u = __builtin_bit_cast(u32, f); return (u & 0x80000000u) ? ~u : (u | 0x80000000u); }
DEV float decf(u32 e) { u32 u = (e & 0x80000000u) ? (e & 0x7FFFFFFFu) : ~e; return __builtin_bit_cast(float, u); }

// ---------------- cast kernels ----------------
__global__ void k_cast(const float* __restrict__ in, u16* __restrict__ out, int n8) {
  int i = blockIdx.x * blockDim.x + threadIdx.x;
  if (i >= n8) return;
  const float4* p = (const float4*)in + (size_t)i * 2;
  float4 a = p[0], b = p[1];
  u16 t[8] = {f2bf(a.x), f2bf(a.y), f2bf(a.z), f2bf(a.w),
              f2bf(b.x), f2bf(b.y), f2bf(b.z), f2bf(b.w)};
  *(uint4*)(out + (size_t)i * 8) = *(uint4*)t;
}

// conv1_w is (512 out, 1024 in); image half = cols [0,512) -> W1a (512x512) bf16
__global__ void k_cast_conv1a(const float* __restrict__ w, u16* __restrict__ out) {
  int i = blockIdx.x * blockDim.x + threadIdx.x; // 32768 threads
  int o = i >> 6, c0 = (i & 63) * 8;
  const float* p = w + (size_t)o * 1024 + c0;
  u16 t[8];
#pragma unroll
  for (int j = 0; j < 8; ++j) t[j] = f2bf(p[j]);
  *(uint4*)(out + (size_t)o * 512 + c0) = *(uint4*)t;
}

// out[r*512+c] = bf16(in[c*512+r])  (512x512)
__global__ __launch_bounds__(256) void k_transpose_cast(const float* __restrict__ in, u16* __restrict__ out) {
  __shared__ float t[32][33];
  int bx = blockIdx.x, by = blockIdx.y;
  int tx = threadIdx.x & 31, ty = threadIdx.x >> 5;
  for (int i = ty; i < 32; i += 8) t[i][tx] = in[(size_t)(by * 32 + i) * 512 + bx * 32 + tx];
  __syncthreads();
  for (int i = ty; i < 32; i += 8) out[(size_t)(bx * 32 + i) * 512 + by * 32 + tx] = f2bf(t[tx][i]);
}

// ---------------- small precompute kernels ----------------
// sent_mean[b,:] = mean_t(sent*mask); biasb[b,o] = sent_mean . conv1_w[o,512:] + conv1_b[o]
__global__ __launch_bounds__(256) void k_sentbias(const float* __restrict__ sent, const float* __restrict__ masks,
                                                  const float* __restrict__ conv1_w, const float* __restrict__ conv1_b,
                                                  float* __restrict__ biasb) {
  int b = blockIdx.x;
  __shared__ float sm[512];
  int tid = threadIdx.x;
  for (int d = tid; d < 512; d += 256) {
    float s = 0.f;
#pragma unroll 8
    for (int t = 0; t < 40; ++t) s += sent[(size_t)b * 40 * 512 + (size_t)t * 512 + d] * masks[b * 40 + t];
    sm[d] = s * (1.0f / 40.0f);
  }
  __syncthreads();
  for (int o = tid; o < 512; o += 256) {
    const float* wr = conv1_w + (size_t)o * 1024 + 512;
    float acc = conv1_b[o];
#pragma unroll 8
    for (int c = 0; c < 512; ++c) acc += sm[c] * wr[c];
    biasb[b * 512 + o] = acc;
  }
}

// biasq[j] = q_w[j,:] . conv2_b + q_b[j]
__global__ void k_biasq(const float* __restrict__ q_w, const float* __restrict__ conv2_b,
                        const float* __restrict__ q_b, float* __restrict__ biasq) {
  int j = blockIdx.x * blockDim.x + threadIdx.x;
  if (j >= 512) return;
  const float* wr = q_w + (size_t)j * 512;
  float acc = q_b[j];
#pragma unroll 8
  for (int d = 0; d < 512; ++d) acc += wr[d] * conv2_b[d];
  biasq[j] = acc;
}

// ---------------- generic bf16 MFMA GEMM: C = X(MxK) @ W(NxK)^T, K=512 ----------------
// biasMode: 0 none, 1 per-col bias[col], 2 per-batch-row bias[(row/196)*512+col]
__global__ __launch_bounds__(256) void k_gemm(const u16* __restrict__ X, const u16* __restrict__ W,
                                              u16* __restrict__ out, const float* __restrict__ bias,
                                              int M, int N, int biasMode) {
  const int K = 512;
  __shared__ u16 Xl[64 * 72];
  __shared__ u16 Wl[64 * 72];
  int tid = threadIdx.x;
  int tileM = blockIdx.x * 64, tileN = blockIdx.y * 64;
  int wave = tid >> 6, lane = tid & 63, quad = lane >> 4, l15 = lane & 15;
  f32x4 z = {0.f, 0.f, 0.f, 0.f};
  f32x4 acc[4] = {z, z, z, z};
  int srow = tid >> 2;
  int sk = (tid & 3) * 16;
  const u16* gx = X + (size_t)(tileM + srow) * K + sk;
  const u16* gw = W + (size_t)(tileN + srow) * K + sk;
  u16* lx = &Xl[srow * 72 + sk];
  u16* lw = &Wl[srow * 72 + sk];
  for (int kc = 0; kc < K; kc += 64) {
    uint4 x0 = *(const uint4*)(gx + kc);
    uint4 x1 = *(const uint4*)(gx + kc + 8);
    uint4 w0 = *(const uint4*)(gw + kc);
    uint4 w1 = *(const uint4*)(gw + kc + 8);
    __syncthreads();
    *(uint4*)lx = x0; *(uint4*)(lx + 8) = x1;
    *(uint4*)lw = w0; *(uint4*)(lw + 8) = w1;
    __syncthreads();
    const u16* ax = &Xl[(wave * 16 + l15) * 72 + quad * 8];
#pragma unroll
    for (int kk = 0; kk < 64; kk += 32) {
      bf16x8 af = *(const bf16x8*)(ax + kk);
#pragma unroll
      for (int nt = 0; nt < 4; ++nt) {
        bf16x8 bfr = *(const bf16x8*)&Wl[(nt * 16 + l15) * 72 + kk + quad * 8];
        acc[nt] = __builtin_amdgcn_mfma_f32_16x16x32_bf16(af, bfr, acc[nt], 0, 0, 0);
      }
    }
  }
  int row0 = tileM + wave * 16 + quad * 4;
#pragma unroll
  for (int nt = 0; nt < 4; ++nt) {
    int col = tileN + nt * 16 + l15;
    float bv = (biasMode == 1) ? bias[col] : 0.0f;
#pragma unroll
    for (int r = 0; r < 4; ++r) {
      int row = row0 + r;
      float v = acc[nt][r] + bv;
      if (biasMode == 2) v += bias[(row / 196) * 512 + col];
      out[(size_t)row * N + col] = f2bf(v);
    }
  }
}

// ---------------- attention: one block per (b,h), thread per l, two-pass softmax ----------------
__global__ __launch_bounds__(256, 1) void k_attn(const u16* __restrict__ qkv, u16* __restrict__ o_out) {
  int bh = blockIdx.x;
  int b = bh >> 3, h = bh & 7;
  __shared__ float Ks[196 * 64]; // 50 KB
  int tid = threadIdx.x;
  const size_t qkvbase = (size_t)b * 196 * 1536 + (size_t)h * 64;
  for (int idx = tid; idx < 196 * 8; idx += 256) {
    int l = idx >> 3, ds = (idx & 7) * 8;
    uint4 kv = *(const uint4*)&qkv[qkvbase + 512 + (size_t)l * 1536 + ds];
    u16 t[8]; *(uint4*)t = kv;
#pragma unroll
    for (int j = 0; j < 8; ++j) Ks[l * 64 + ds + j] = bf2f(t[j]);
  }
  float q[64];
  int l = tid;
  bool act = l < 196;
  if (act) {
#pragma unroll
    for (int ds = 0; ds < 64; ds += 8) {
      uint4 qv = *(const uint4*)&qkv[qkvbase + (size_t)l * 1536 + ds];
      u16 t[8]; *(uint4*)t = qv;
#pragma unroll
      for (int j = 0; j < 8; ++j) q[ds + j] = bf2f(t[j]);
    }
  }
  __syncthreads();
  float mx = -3e38f;
  if (act) {
    for (int m = 0; m < 196; ++m) {
      float s = 0.f;
#pragma unroll
      for (int d = 0; d < 64; ++d) s += q[d] * Ks[m * 64 + d];
      mx = fmaxf(mx, s);
    }
    float o[64];
#pragma unroll
    for (int d = 0; d < 64; ++d) o[d] = 0.f;
    float denom = 0.f;
    for (int m = 0; m < 196; ++m) {
      float s = 0.f;
#pragma unroll
      for (int d = 0; d < 64; ++d) s += q[d] * Ks[m * 64 + d];
      float p = __expf((s - mx) * 0.125f);
      denom += p;
      const u16* vrow = &qkv[qkvbase + 1024 + (size_t)m * 1536];
#pragma unroll
      for (int ds = 0; ds < 64; ds += 8) {
        uint4 vv = *(const uint4*)(vrow + ds);
        u16 t[8]; *(uint4*)t = vv;
#pragma unroll
        for (int j = 0; j < 8; ++j) o[ds + j] += p * bf2f(t[j]);
      }
    }
    float inv = 1.0f / denom;
    size_t ob = (size_t)b * 196 * 512 + (size_t)l * 512 + (size_t)h * 64;
#pragma unroll
    for (int d = 0; d < 64; ++d) o_out[ob + d] = f2bf(o[d] * inv);
  }
}

// ---------------- init for reduction buffers ----------------
__global__ void k_init(float* __restrict__ t2v, u32* __restrict__ colmax) {
  int i = blockIdx.x * blockDim.x + threadIdx.x;
  if (i < 1024) t2v[i] = 0.f;
  if (i < 32 * 32 * 196) colmax[i] = 0u; // enc==0 is below any real float's encoding
}

// ---------------- logits tile + row/col max reductions ----------------
// grid (32,32,4): block computes 64 QL-rows x 208 KL-cols for (a,b), K=512
__global__ __launch_bounds__(256) void k_logits(const u16* __restrict__ QL, const u16* __restrict__ KL,
                                                float* __restrict__ t2v, u32* __restrict__ colmax) {
  int a = blockIdx.x, b = blockIdx.y, lc = blockIdx.z;
  __shared__ u16 Ql[64 * 72];   // 9.2 KB
  __shared__ u16 Kl[208 * 72];  // 30 KB
  __shared__ float colred[4 * 208];
  int tid = threadIdx.x;
  int wave = tid >> 6, lane = tid & 63, quad = lane >> 4, l15 = lane & 15;
  f32x4 z = {0.f, 0.f, 0.f, 0.f};
  f32x4 acc[13];
#pragma unroll
  for (int i = 0; i < 13; ++i) acc[i] = z;
  const int K = 512;
  int lbase = lc * 64;
  bool active = (lbase + wave * 16) < 196;
  int srow = tid >> 2, sk = (tid & 3) * 16;
  for (int kc = 0; kc < K; kc += 64) {
    int qrow = lbase + srow;
    uint4 q0 = {0, 0, 0, 0}, q1 = {0, 0, 0, 0};
    if (qrow < 196) {
      const u16* g = QL + (size_t)a * 196 * 512 + (size_t)qrow * 512 + kc + sk;
      q0 = *(const uint4*)g; q1 = *(const uint4*)(g + 8);
    }
    __syncthreads();
    *(uint4*)&Ql[srow * 72 + sk] = q0;
    *(uint4*)&Ql[srow * 72 + sk + 8] = q1;
    for (int idx = tid; idx < 208 * 4; idx += 256) {
      int r = idx >> 2, ks2 = (idx & 3) * 16;
      uint4 v0 = {0, 0, 0, 0}, v1 = {0, 0, 0, 0};
      if (r < 196) {
        const u16* g = KL + (size_t)b * 196 * 512 + (size_t)r * 512 + kc + ks2;
        v0 = *(const uint4*)g; v1 = *(const uint4*)(g + 8);
      }
      *(uint4*)&Kl[r * 72 + ks2] = v0;
      *(uint4*)&Kl[r * 72 + ks2 + 8] = v1;
    }
    __syncthreads();
    if (active) {
#pragma unroll
      for (int kk = 0; kk < 64; kk += 32) {
        bf16x8 af = *(const bf16x8*)&Ql[(wave * 16 + l15) * 72 + kk + quad * 8];
#pragma unroll
        for (int nt = 0; nt < 13; ++nt) {
          bf16x8 bfr = *(const bf16x8*)&Kl[(nt * 16 + l15) * 72 + kk + quad * 8];
          acc[nt] = __builtin_amdgcn_mfma_f32_16x16x32_bf16(af, bfr, acc[nt], 0, 0, 0);
        }
      }
    }
  }
  // ---- t2v: rowmax then sum over rows ----
  if (active) {
    float rsum = 0.f;
#pragma unroll
    for (int r = 0; r < 4; ++r) {
      int row = lbase + wave * 16 + quad * 4 + r;
      float m = -3e38f;
#pragma unroll
      for (int nt = 0; nt < 13; ++nt) {
        int c = nt * 16 + l15;
        if (c < 196) m = fmaxf(m, acc[nt][r]);
      }
#pragma unroll
      for (int off = 8; off > 0; off >>= 1) m = fmaxf(m, __shfl_xor(m, off, 16));
      if (row < 196) rsum += m;
    }
    rsum += __shfl_xor(rsum, 16);
    rsum += __shfl_xor(rsum, 32);
    if (lane == 0) atomicAdd(&t2v[a * 32 + b], rsum);
  }
  // ---- colmax within block -> LDS -> global atomicMax ----
  if (active) {
#pragma unroll
    for (int nt = 0; nt < 13; ++nt) {
      float cm = -3e38f;
#pragma unroll
      for (int r = 0; r < 4; ++r) {
        int row = lbase + wave * 16 + quad * 4 + r;
        if (row < 196) cm = fmaxf(cm, acc[nt][r]);
      }
      cm = fmaxf(cm, __shfl_xor(cm, 16));
      cm = fmaxf(cm, __shfl_xor(cm, 32));
      if (quad == 0) colred[wave * 208 + nt * 16 + l15] = cm;
    }
  } else {
    if (quad == 0)
      for (int c = l15; c < 208; c += 16) colred[wave * 208 + c] = -3e38f;
  }
  __syncthreads();
  for (int c = tid; c < 196; c += 256) {
    float m = fmaxf(fmaxf(colred[c], colred[208 + c]), fmaxf(colred[416 + c], colred[624 + c]));
    atomicMax(&colmax[((size_t)a * 32 + b) * 196 + c], encf(m));
  }
}

// ---------------- final: S matrix + symmetric cross-entropy ----------------
__global__ __launch_bounds__(256) void k_final(const float* __restrict__ t2v, const u32* __restrict__ colmax,
                                               const float* __restrict__ logit_scale, float* __restrict__ out) {
  __shared__ float S[1024];
  __shared__ float terms[64];
  int tid = threadIdx.x;
  float sc = 0.5f * __expf(logit_scale[0]);
  for (int pair = tid; pair < 1024; pair += 256) {
    const u32* cp = colmax + (size_t)pair * 196;
    float s = 0.f;
#pragma unroll 4
    for (int m = 0; m < 196; ++m) s += decf(cp[m]);
    S[pair] = sc * (t2v[pair] + s) * (1.0f / 196.0f);
  }
  __syncthreads();
  if (tid < 64) {
    int aa = tid & 31;
    bool rowMode = tid < 32;
    float mx = -3e38f;
    for (int j = 0; j < 32; ++j) {
      float v = rowMode ? S[aa * 32 + j] : S[j * 32 + aa];
      mx = fmaxf(mx, v);
    }
    float se = 0.f;
    for (int j = 0; j < 32; ++j) {
      float v = rowMode ? S[aa * 32 + j] : S[j * 32 + aa];
      se += __expf(v - mx);
    }
    terms[tid] = S[aa * 33] - (mx + logf(se));
  }
  __syncthreads();
  if (tid == 0) {
    float s = 0.f;
    for (int i = 0; i < 64; ++i) s += terms[i];
    out[0] = -s * (1.0f / 64.0f);
  }
}

// ---------------- host ----------------
extern "C" void kernel_launch(void* const* d_in, const int* in_sizes, int n_in,
                              void* d_out, int out_size, void* d_ws, size_t ws_size,
                              hipStream_t stream) {
  const float* bef       = (const float*)d_in[0];
  const float* sent      = (const float*)d_in[1];
  const float* aft       = (const float*)d_in[2];
  const float* masks     = (const float*)d_in[3];
  const float* conv1_w   = (const float*)d_in[4];
  const float* conv1_b   = (const float*)d_in[5];
  const float* in_proj_w = (const float*)d_in[6];
  const float* out_proj_w= (const float*)d_in[7];
  const float* conv2_w   = (const float*)d_in[8];
  const float* conv2_b   = (const float*)d_in[9];
  const float* q_w       = (const float*)d_in[10];
  const float* q_b       = (const float*)d_in[11];
  const float* k_w       = (const float*)d_in[12];
  const float* k_b       = (const float*)d_in[13];
  const float* logit_scale = (const float*)d_in[14];
  float* out = (float*)d_out;

  char* ws = (char*)d_ws;
  size_t off = 0;
  auto alloc = [&](size_t bytes) -> char* {
    char* p = ws + off;
    off += (bytes + 255) & ~(size_t)255;
    return p;
  };
  const size_t MROWS = 32 * 196; // 6272
  u16* bef16    = (u16*)alloc(MROWS * 512 * 2);
  u16* aft16    = (u16*)alloc(MROWS * 512 * 2);
  u16* w1a16    = (u16*)alloc(512 * 512 * 2);
  u16* inproj16 = (u16*)alloc(1536 * 512 * 2);
  u16* kw16     = (u16*)alloc(512 * 512 * 2);
  u16* qw16     = (u16*)alloc(512 * 512 * 2);
  u16* wcT16    = (u16*)alloc(512 * 512 * 2);
  u16* woT16    = (u16*)alloc(512 * 512 * 2);
  u16* wt16     = (u16*)alloc(512 * 512 * 2);
  u16* wcomb16  = (u16*)alloc(512 * 512 * 2);
  float* biasb  = (float*)alloc(32 * 512 * 4);
  float* biasq  = (float*)alloc(512 * 4);
  u16* v116     = (u16*)alloc(MROWS * 512 * 2);
  u16* qkv16    = (u16*)alloc(MROWS * 1536 * 2);
  u16* oattn16  = (u16*)alloc(MROWS * 512 * 2);
  u16* QL16     = (u16*)alloc(MROWS * 512 * 2);
  u16* KL16     = (u16*)alloc(MROWS * 512 * 2);
  float* t2v    = (float*)alloc(1024 * 4);
  u32* colmax   = (u32*)alloc(32 * 32 * 196 * 4);

  // casts
  k_cast<<<1568, 256, 0, stream>>>(bef, bef16, 401408);
  k_cast<<<1568, 256, 0, stream>>>(aft, aft16, 401408);
  k_cast<<<384, 256, 0, stream>>>(in_proj_w, inproj16, 98304);
  k_cast<<<128, 256, 0, stream>>>(k_w, kw16, 32768);
  k_cast<<<128, 256, 0, stream>>>(q_w, qw16, 32768);
  k_cast_conv1a<<<128, 256, 0, stream>>>(conv1_w, w1a16);
  k_transpose_cast<<<dim3(16, 16), 256, 0, stream>>>(conv2_w, wcT16);
  k_transpose_cast<<<dim3(16, 16), 256, 0, stream>>>(out_proj_w, woT16);
  // small precomputes
  k_sentbias<<<32, 256, 0, stream>>>(sent, masks, conv1_w, conv1_b, biasb);
  k_biasq<<<2, 256, 0, stream>>>(q_w, conv2_b, q_b, biasq);
  // weight composition: Wcomb = Wq @ Wc @ Wo
  k_gemm<<<dim3(8, 8), 256, 0, stream>>>(qw16, wcT16, wt16, nullptr, 512, 512, 0);
  k_gemm<<<dim3(8, 8), 256, 0, stream>>>(wt16, woT16, wcomb16, nullptr, 512, 512, 0);
  // v1 = bef @ W1a^T + biasb[b]
  k_gemm<<<dim3(98, 8), 256, 0, stream>>>(bef16, w1a16, v116, biasb, 6272, 512, 2);
  // qkv = v1 @ in_proj^T
  k_gemm<<<dim3(98, 24), 256, 0, stream>>>(v116, inproj16, qkv16, nullptr, 6272, 1536, 0);
  // attention
  k_attn<<<256, 256, 0, stream>>>(qkv16, oattn16);
  // QL = o_attn @ Wcomb^T + biasq ;  KL = aft @ k_w^T + k_b
  k_gemm<<<dim3(98, 8), 256, 0, stream>>>(oattn16, wcomb16, QL16, biasq, 6272, 512, 1);
  k_gemm<<<dim3(98, 8), 256, 0, stream>>>(aft16, kw16, KL16, k_b, 6272, 512, 1);
  // logits reductions
  k_init<<<784, 256, 0, stream>>>(t2v, colmax);
  k_logits<<<dim3(32, 32, 4), 256, 0, stream>>>(QL16, KL16, t2v, colmax);
  // final loss
  k_final<<<1, 256, 0, stream>>>(t2v, colmax, logit_scale, out);
}

// Round 2
// 502.969 us; speedup vs baseline: 1.2929x; 1.2929x over previous
//
#include <hip/hip_runtime.h>

// B=32, LV=196, LT=40, D=512, H=8, DH=64
// ws layout: ~60 MB of bf16 intermediates (see kernel_launch).

typedef unsigned int u32;
typedef unsigned short u16;
typedef __attribute__((ext_vector_type(8))) short bf16x8;
typedef __attribute__((ext_vector_type(4))) float f32x4;

#define DEV __device__ __forceinline__

DEV u16 f2bf(float f) {
  u32 u = __builtin_bit_cast(u32, f);
  u = (u + 0x7FFFu + ((u >> 16) & 1u)) >> 16;
  return (u16)u;
}
DEV float bf2f(u16 h) { u32 u = ((u32)h) << 16; return __builtin_bit_cast(float, u); }
// monotonic float<->u32 encoding for atomicMax on floats (enc(x)>enc(y) iff x>y)
DEV u32 encf(float f) { u32 u = __builtin_bit_cast(u32, f); return (u & 0x80000000u) ? ~u : (u | 0x80000000u); }
DEV float decf(u32 e) { u32 u = (e & 0x80000000u) ? (e & 0x7FFFFFFFu) : ~e; return __builtin_bit_cast(float, u); }

// ---------------- cast kernels ----------------
__global__ void k_cast(const float* __restrict__ in, u16* __restrict__ out, int n8) {
  int i = blockIdx.x * blockDim.x + threadIdx.x;
  if (i >= n8) return;
  const float4* p = (const float4*)in + (size_t)i * 2;
  float4 a = p[0], b = p[1];
  u16 t[8] = {f2bf(a.x), f2bf(a.y), f2bf(a.z), f2bf(a.w),
              f2bf(b.x), f2bf(b.y), f2bf(b.z), f2bf(b.w)};
  *(uint4*)(out + (size_t)i * 8) = *(uint4*)t;
}

// conv1_w is (512 out, 1024 in); image half = cols [0,512) -> W1a (512x512) bf16
__global__ void k_cast_conv1a(const float* __restrict__ w, u16* __restrict__ out) {
  int i = blockIdx.x * blockDim.x + threadIdx.x; // 32768 threads
  int o = i >> 6, c0 = (i & 63) * 8;
  const float* p = w + (size_t)o * 1024 + c0;
  u16 t[8];
#pragma unroll
  for (int j = 0; j < 8; ++j) t[j] = f2bf(p[j]);
  *(uint4*)(out + (size_t)o * 512 + c0) = *(uint4*)t;
}

// out[r*512+c] = bf16(in[c*512+r])  (512x512)
__global__ __launch_bounds__(256) void k_transpose_cast(const float* __restrict__ in, u16* __restrict__ out) {
  __shared__ float t[32][33];
  int bx = blockIdx.x, by = blockIdx.y;
  int tx = threadIdx.x & 31, ty = threadIdx.x >> 5;
  for (int i = ty; i < 32; i += 8) t[i][tx] = in[(size_t)(by * 32 + i) * 512 + bx * 32 + tx];
  __syncthreads();
  for (int i = ty; i < 32; i += 8) out[(size_t)(bx * 32 + i) * 512 + by * 32 + tx] = f2bf(t[tx][i]);
}

// ---------------- small precompute kernels ----------------
__global__ __launch_bounds__(256) void k_sentbias(const float* __restrict__ sent, const float* __restrict__ masks,
                                                  const float* __restrict__ conv1_w, const float* __restrict__ conv1_b,
                                                  float* __restrict__ biasb) {
  int b = blockIdx.x;
  __shared__ float sm[512];
  int tid = threadIdx.x;
  for (int d = tid; d < 512; d += 256) {
    float s = 0.f;
#pragma unroll 8
    for (int t = 0; t < 40; ++t) s += sent[(size_t)b * 40 * 512 + (size_t)t * 512 + d] * masks[b * 40 + t];
    sm[d] = s * (1.0f / 40.0f);
  }
  __syncthreads();
  for (int o = tid; o < 512; o += 256) {
    const float* wr = conv1_w + (size_t)o * 1024 + 512;
    float acc = conv1_b[o];
#pragma unroll 8
    for (int c = 0; c < 512; ++c) acc += sm[c] * wr[c];
    biasb[b * 512 + o] = acc;
  }
}

__global__ void k_biasq(const float* __restrict__ q_w, const float* __restrict__ conv2_b,
                        const float* __restrict__ q_b, float* __restrict__ biasq) {
  int j = blockIdx.x * blockDim.x + threadIdx.x;
  if (j >= 512) return;
  const float* wr = q_w + (size_t)j * 512;
  float acc = q_b[j];
#pragma unroll 8
  for (int d = 0; d < 512; ++d) acc += wr[d] * conv2_b[d];
  biasq[j] = acc;
}

// ---------------- generic bf16 MFMA GEMM: C = X(MxK) @ W(NxK)^T, K=512 ----------------
// biasMode: 0 none, 1 per-col bias[col], 2 per-batch-row bias[(row/196)*512+col]
__global__ __launch_bounds__(256) void k_gemm(const u16* __restrict__ X, const u16* __restrict__ W,
                                              u16* __restrict__ out, const float* __restrict__ bias,
                                              int M, int N, int biasMode) {
  const int K = 512;
  __shared__ u16 Xl[64 * 72];
  __shared__ u16 Wl[64 * 72];
  int tid = threadIdx.x;
  int tileM = blockIdx.x * 64, tileN = blockIdx.y * 64;
  int wave = tid >> 6, lane = tid & 63, quad = lane >> 4, l15 = lane & 15;
  f32x4 z = {0.f, 0.f, 0.f, 0.f};
  f32x4 acc[4] = {z, z, z, z};
  int srow = tid >> 2;
  int sk = (tid & 3) * 16;
  const u16* gx = X + (size_t)(tileM + srow) * K + sk;
  const u16* gw = W + (size_t)(tileN + srow) * K + sk;
  u16* lx = &Xl[srow * 72 + sk];
  u16* lw = &Wl[srow * 72 + sk];
  for (int kc = 0; kc < K; kc += 64) {
    uint4 x0 = *(const uint4*)(gx + kc);
    uint4 x1 = *(const uint4*)(gx + kc + 8);
    uint4 w0 = *(const uint4*)(gw + kc);
    uint4 w1 = *(const uint4*)(gw + kc + 8);
    __syncthreads();
    *(uint4*)lx = x0; *(uint4*)(lx + 8) = x1;
    *(uint4*)lw = w0; *(uint4*)(lw + 8) = w1;
    __syncthreads();
    const u16* ax = &Xl[(wave * 16 + l15) * 72 + quad * 8];
#pragma unroll
    for (int kk = 0; kk < 64; kk += 32) {
      bf16x8 af = *(const bf16x8*)(ax + kk);
#pragma unroll
      for (int nt = 0; nt < 4; ++nt) {
        bf16x8 bfr = *(const bf16x8*)&Wl[(nt * 16 + l15) * 72 + kk + quad * 8];
        acc[nt] = __builtin_amdgcn_mfma_f32_16x16x32_bf16(af, bfr, acc[nt], 0, 0, 0);
      }
    }
  }
  int row0 = tileM + wave * 16 + quad * 4;
#pragma unroll
  for (int nt = 0; nt < 4; ++nt) {
    int col = tileN + nt * 16 + l15;
    float bv = (biasMode == 1) ? bias[col] : 0.0f;
#pragma unroll
    for (int r = 0; r < 4; ++r) {
      int row = row0 + r;
      float v = acc[nt][r] + bv;
      if (biasMode == 2) v += bias[(row / 196) * 512 + col];
      out[(size_t)row * N + col] = f2bf(v);
    }
  }
}

// ---------------- MFMA attention: one block (4 waves) per (b,h) ----------------
// LDS: Ks (K, [pos][feat], stride 72), Vt (V^T, [feat][pos], stride 232),
//      Ps (per-wave normalized P strip, bf16, [row16][pos], stride 232).
// Strides: row-byte multiples of 16 (b128-aligned); bank aliasing <=2-way (free).
__global__ __launch_bounds__(256, 1) void k_attn2(const u16* __restrict__ qkv, u16* __restrict__ o_out) {
  const int b = blockIdx.x >> 3, h = blockIdx.x & 7;
  __shared__ u16 Ks[208 * 72];       // 29,952 B
  __shared__ u16 Vt[64 * 232];       // 29,696 B
  __shared__ u16 Ps[4][16 * 232];    // 29,696 B  (total ~89 KB)
  const int tid = threadIdx.x;
  const int wave = tid >> 6, lane = tid & 63, quad = lane >> 4, l15 = lane & 15;
  const size_t base = (size_t)b * 196 * 1536 + (size_t)h * 64;

  // phase 0: zero-fill Vt (pads) and Ps pad cols [208,232)
  for (int i = tid; i < 64 * 232 / 4; i += 256) ((unsigned long long*)Vt)[i] = 0ULL;
  for (int i = tid; i < 4 * 16 * 24; i += 256) {
    int w = i / 384, rem = i - w * 384;
    int r = rem / 24, c = rem - r * 24;
    Ps[w][r * 232 + 208 + c] = 0;
  }
  __syncthreads();

  // phase 1: stage K (rows >=196 zeroed), transpose V into Vt, prefetch Q frags
  for (int idx = tid; idx < 208 * 8; idx += 256) {
    int r = idx >> 3, c = (idx & 7) * 8;
    uint4 v = {0, 0, 0, 0};
    if (r < 196) v = *(const uint4*)&qkv[base + 512 + (size_t)r * 1536 + c];
    *(uint4*)&Ks[r * 72 + c] = v;
  }
  for (int idx = tid; idx < 196 * 8; idx += 256) {
    int p = idx >> 3, f0 = (idx & 7) * 8;
    uint4 v = *(const uint4*)&qkv[base + 1024 + (size_t)p * 1536 + f0];
    u16 t[8]; *(uint4*)t = v;
#pragma unroll
    for (int j = 0; j < 8; ++j) Vt[(f0 + j) * 232 + p] = t[j];
  }
  bf16x8 qz = {0, 0, 0, 0, 0, 0, 0, 0};
  bf16x8 qf[4][2];
#pragma unroll
  for (int i = 0; i < 4; ++i) {
    int s = wave + i * 4;
    int row = s * 16 + l15;
#pragma unroll
    for (int c = 0; c < 2; ++c) {
      bf16x8 v = qz;
      if (s < 13 && row < 196)
        v = *(const bf16x8*)&qkv[base + (size_t)row * 1536 + c * 32 + quad * 8];
      qf[i][c] = v;
    }
  }
  __syncthreads();

  const f32x4 z = {0.f, 0.f, 0.f, 0.f};
  for (int i = 0; i < 4; ++i) {
    int s = wave + i * 4;
    if (s >= 13) break;
    // scores: 16 rows x 208 cols
    f32x4 acc[13];
#pragma unroll
    for (int nt = 0; nt < 13; ++nt) acc[nt] = z;
#pragma unroll
    for (int c = 0; c < 2; ++c) {
      bf16x8 a = qf[i][c];
#pragma unroll
      for (int nt = 0; nt < 13; ++nt) {
        bf16x8 bfr = *(const bf16x8*)&Ks[(nt * 16 + l15) * 72 + c * 32 + quad * 8];
        acc[nt] = __builtin_amdgcn_mfma_f32_16x16x32_bf16(a, bfr, acc[nt], 0, 0, 0);
      }
    }
    // softmax over cols, normalize, write bf16 P to Ps[wave] (C-layout -> LDS)
#pragma unroll
    for (int r = 0; r < 4; ++r) {
      float m = -3e38f;
#pragma unroll
      for (int nt = 0; nt < 13; ++nt) {
        float sv = acc[nt][r] * 0.125f;
        acc[nt][r] = sv;
        if (nt < 12 || l15 < 4) m = fmaxf(m, sv);
      }
#pragma unroll
      for (int off = 1; off < 16; off <<= 1) m = fmaxf(m, __shfl_xor(m, off));
      float ssum = 0.f;
#pragma unroll
      for (int nt = 0; nt < 13; ++nt) {
        float p = (nt < 12 || l15 < 4) ? __expf(acc[nt][r] - m) : 0.f;
        acc[nt][r] = p;
        ssum += p;
      }
#pragma unroll
      for (int off = 1; off < 16; off <<= 1) ssum += __shfl_xor(ssum, off);
      float is = 1.0f / ssum;
      int row = quad * 4 + r;
#pragma unroll
      for (int nt = 0; nt < 13; ++nt) {
        float v = acc[nt][r] * is;
        float vx = __shfl_xor(v, 1);
        if ((l15 & 1) == 0) {
          u32 pk = (u32)f2bf(v) | ((u32)f2bf(vx) << 16);
          *(u32*)&Ps[wave][row * 232 + nt * 16 + l15] = pk;
        }
      }
    }
    // O = P @ V  (A-frag from Ps, B-frag from Vt), 7 k-chunks of 32 (cols 0..223)
    f32x4 oacc[4] = {z, z, z, z};
#pragma unroll
    for (int kc = 0; kc < 7; ++kc) {
      bf16x8 a = *(const bf16x8*)&Ps[wave][l15 * 232 + kc * 32 + quad * 8];
#pragma unroll
      for (int nt = 0; nt < 4; ++nt) {
        bf16x8 bfr = *(const bf16x8*)&Vt[(nt * 16 + l15) * 232 + kc * 32 + quad * 8];
        oacc[nt] = __builtin_amdgcn_mfma_f32_16x16x32_bf16(a, bfr, oacc[nt], 0, 0, 0);
      }
    }
#pragma unroll
    for (int nt = 0; nt < 4; ++nt) {
#pragma unroll
      for (int r = 0; r < 4; ++r) {
        int row = s * 16 + quad * 4 + r;
        if (row < 196)
          o_out[((size_t)b * 196 + row) * 512 + h * 64 + nt * 16 + l15] = f2bf(oacc[nt][r]);
      }
    }
  }
}

// ---------------- init for reduction buffers ----------------
__global__ void k_init(float* __restrict__ t2v, u32* __restrict__ colmax) {
  int i = blockIdx.x * blockDim.x + threadIdx.x;
  if (i < 1024) t2v[i] = 0.f;
  if (i < 32 * 32 * 196) colmax[i] = 0u;
}

// ---------------- logits tile + row/col max reductions ----------------
__global__ __launch_bounds__(256) void k_logits(const u16* __restrict__ QL, const u16* __restrict__ KL,
                                                float* __restrict__ t2v, u32* __restrict__ colmax) {
  int a = blockIdx.x, b = blockIdx.y, lc = blockIdx.z;
  __shared__ u16 Ql[64 * 72];
  __shared__ u16 Kl[208 * 72];
  __shared__ float colred[4 * 208];
  int tid = threadIdx.x;
  int wave = tid >> 6, lane = tid & 63, quad = lane >> 4, l15 = lane & 15;
  f32x4 z = {0.f, 0.f, 0.f, 0.f};
  f32x4 acc[13];
#pragma unroll
  for (int i = 0; i < 13; ++i) acc[i] = z;
  const int K = 512;
  int lbase = lc * 64;
  bool active = (lbase + wave * 16) < 196;
  int srow = tid >> 2, sk = (tid & 3) * 16;
  for (int kc = 0; kc < K; kc += 64) {
    int qrow = lbase + srow;
    uint4 q0 = {0, 0, 0, 0}, q1 = {0, 0, 0, 0};
    if (qrow < 196) {
      const u16* g = QL + (size_t)a * 196 * 512 + (size_t)qrow * 512 + kc + sk;
      q0 = *(const uint4*)g; q1 = *(const uint4*)(g + 8);
    }
    __syncthreads();
    *(uint4*)&Ql[srow * 72 + sk] = q0;
    *(uint4*)&Ql[srow * 72 + sk + 8] = q1;
    for (int idx = tid; idx < 208 * 4; idx += 256) {
      int r = idx >> 2, ks2 = (idx & 3) * 16;
      uint4 v0 = {0, 0, 0, 0}, v1 = {0, 0, 0, 0};
      if (r < 196) {
        const u16* g = KL + (size_t)b * 196 * 512 + (size_t)r * 512 + kc + ks2;
        v0 = *(const uint4*)g; v1 = *(const uint4*)(g + 8);
      }
      *(uint4*)&Kl[r * 72 + ks2] = v0;
      *(uint4*)&Kl[r * 72 + ks2 + 8] = v1;
    }
    __syncthreads();
    if (active) {
#pragma unroll
      for (int kk = 0; kk < 64; kk += 32) {
        bf16x8 af = *(const bf16x8*)&Ql[(wave * 16 + l15) * 72 + kk + quad * 8];
#pragma unroll
        for (int nt = 0; nt < 13; ++nt) {
          bf16x8 bfr = *(const bf16x8*)&Kl[(nt * 16 + l15) * 72 + kk + quad * 8];
          acc[nt] = __builtin_amdgcn_mfma_f32_16x16x32_bf16(af, bfr, acc[nt], 0, 0, 0);
        }
      }
    }
  }
  if (active) {
    float rsum = 0.f;
#pragma unroll
    for (int r = 0; r < 4; ++r) {
      int row = lbase + wave * 16 + quad * 4 + r;
      float m = -3e38f;
#pragma unroll
      for (int nt = 0; nt < 13; ++nt) {
        int c = nt * 16 + l15;
        if (c < 196) m = fmaxf(m, acc[nt][r]);
      }
#pragma unroll
      for (int off = 8; off > 0; off >>= 1) m = fmaxf(m, __shfl_xor(m, off, 16));
      if (row < 196) rsum += m;
    }
    rsum += __shfl_xor(rsum, 16);
    rsum += __shfl_xor(rsum, 32);
    if (lane == 0) atomicAdd(&t2v[a * 32 + b], rsum);
  }
  if (active) {
#pragma unroll
    for (int nt = 0; nt < 13; ++nt) {
      float cm = -3e38f;
#pragma unroll
      for (int r = 0; r < 4; ++r) {
        int row = lbase + wave * 16 + quad * 4 + r;
        if (row < 196) cm = fmaxf(cm, acc[nt][r]);
      }
      cm = fmaxf(cm, __shfl_xor(cm, 16));
      cm = fmaxf(cm, __shfl_xor(cm, 32));
      if (quad == 0) colred[wave * 208 + nt * 16 + l15] = cm;
    }
  } else {
    if (quad == 0)
      for (int c = l15; c < 208; c += 16) colred[wave * 208 + c] = -3e38f;
  }
  __syncthreads();
  for (int c = tid; c < 196; c += 256) {
    float m = fmaxf(fmaxf(colred[c], colred[208 + c]), fmaxf(colred[416 + c], colred[624 + c]));
    atomicMax(&colmax[((size_t)a * 32 + b) * 196 + c], encf(m));
  }
}

// ---------------- final: S matrix + symmetric cross-entropy ----------------
__global__ __launch_bounds__(256) void k_final(const float* __restrict__ t2v, const u32* __restrict__ colmax,
                                               const float* __restrict__ logit_scale, float* __restrict__ out) {
  __shared__ float S[1024];
  __shared__ float terms[64];
  int tid = threadIdx.x;
  float sc = 0.5f * __expf(logit_scale[0]);
  for (int pair = tid; pair < 1024; pair += 256) {
    const u32* cp = colmax + (size_t)pair * 196;
    float s = 0.f;
#pragma unroll 4
    for (int m = 0; m < 196; ++m) s += decf(cp[m]);
    S[pair] = sc * (t2v[pair] + s) * (1.0f / 196.0f);
  }
  __syncthreads();
  if (tid < 64) {
    int aa = tid & 31;
    bool rowMode = tid < 32;
    float mx = -3e38f;
    for (int j = 0; j < 32; ++j) {
      float v = rowMode ? S[aa * 32 + j] : S[j * 32 + aa];
      mx = fmaxf(mx, v);
    }
    float se = 0.f;
    for (int j = 0; j < 32; ++j) {
      float v = rowMode ? S[aa * 32 + j] : S[j * 32 + aa];
      se += __expf(v - mx);
    }
    terms[tid] = S[aa * 33] - (mx + logf(se));
  }
  __syncthreads();
  if (tid == 0) {
    float s = 0.f;
    for (int i = 0; i < 64; ++i) s += terms[i];
    out[0] = -s * (1.0f / 64.0f);
  }
}

// ---------------- host ----------------
extern "C" void kernel_launch(void* const* d_in, const int* in_sizes, int n_in,
                              void* d_out, int out_size, void* d_ws, size_t ws_size,
                              hipStream_t stream) {
  const float* bef       = (const float*)d_in[0];
  const float* sent      = (const float*)d_in[1];
  const float* aft       = (const float*)d_in[2];
  const float* masks     = (const float*)d_in[3];
  const float* conv1_w   = (const float*)d_in[4];
  const float* conv1_b   = (const float*)d_in[5];
  const float* in_proj_w = (const float*)d_in[6];
  const float* out_proj_w= (const float*)d_in[7];
  const float* conv2_w   = (const float*)d_in[8];
  const float* conv2_b   = (const float*)d_in[9];
  const float* q_w       = (const float*)d_in[10];
  const float* q_b       = (const float*)d_in[11];
  const float* k_w       = (const float*)d_in[12];
  const float* k_b       = (const float*)d_in[13];
  const float* logit_scale = (const float*)d_in[14];
  float* out = (float*)d_out;

  char* ws = (char*)d_ws;
  size_t off = 0;
  auto alloc = [&](size_t bytes) -> char* {
    char* p = ws + off;
    off += (bytes + 255) & ~(size_t)255;
    return p;
  };
  const size_t MROWS = 32 * 196; // 6272
  u16* bef16    = (u16*)alloc(MROWS * 512 * 2);
  u16* aft16    = (u16*)alloc(MROWS * 512 * 2);
  u16* w1a16    = (u16*)alloc(512 * 512 * 2);
  u16* inproj16 = (u16*)alloc(1536 * 512 * 2);
  u16* kw16     = (u16*)alloc(512 * 512 * 2);
  u16* qw16     = (u16*)alloc(512 * 512 * 2);
  u16* wcT16    = (u16*)alloc(512 * 512 * 2);
  u16* woT16    = (u16*)alloc(512 * 512 * 2);
  u16* wt16     = (u16*)alloc(512 * 512 * 2);
  u16* wcomb16  = (u16*)alloc(512 * 512 * 2);
  float* biasb  = (float*)alloc(32 * 512 * 4);
  float* biasq  = (float*)alloc(512 * 4);
  u16* v116     = (u16*)alloc(MROWS * 512 * 2);
  u16* qkv16    = (u16*)alloc(MROWS * 1536 * 2);
  u16* oattn16  = (u16*)alloc(MROWS * 512 * 2);
  u16* QL16     = (u16*)alloc(MROWS * 512 * 2);
  u16* KL16     = (u16*)alloc(MROWS * 512 * 2);
  float* t2v    = (float*)alloc(1024 * 4);
  u32* colmax   = (u32*)alloc(32 * 32 * 196 * 4);

  // casts
  k_cast<<<1568, 256, 0, stream>>>(bef, bef16, 401408);
  k_cast<<<1568, 256, 0, stream>>>(aft, aft16, 401408);
  k_cast<<<384, 256, 0, stream>>>(in_proj_w, inproj16, 98304);
  k_cast<<<128, 256, 0, stream>>>(k_w, kw16, 32768);
  k_cast<<<128, 256, 0, stream>>>(q_w, qw16, 32768);
  k_cast_conv1a<<<128, 256, 0, stream>>>(conv1_w, w1a16);
  k_transpose_cast<<<dim3(16, 16), 256, 0, stream>>>(conv2_w, wcT16);
  k_transpose_cast<<<dim3(16, 16), 256, 0, stream>>>(out_proj_w, woT16);
  // small precomputes
  k_sentbias<<<32, 256, 0, stream>>>(sent, masks, conv1_w, conv1_b, biasb);
  k_biasq<<<2, 256, 0, stream>>>(q_w, conv2_b, q_b, biasq);
  // weight composition: Wcomb = Wq @ Wc @ Wo
  k_gemm<<<dim3(8, 8), 256, 0, stream>>>(qw16, wcT16, wt16, nullptr, 512, 512, 0);
  k_gemm<<<dim3(8, 8), 256, 0, stream>>>(wt16, woT16, wcomb16, nullptr, 512, 512, 0);
  // v1 = bef @ W1a^T + biasb[b]
  k_gemm<<<dim3(98, 8), 256, 0, stream>>>(bef16, w1a16, v116, biasb, 6272, 512, 2);
  // qkv = v1 @ in_proj^T
  k_gemm<<<dim3(98, 24), 256, 0, stream>>>(v116, inproj16, qkv16, nullptr, 6272, 1536, 0);
  // attention (MFMA)
  k_attn2<<<256, 256, 0, stream>>>(qkv16, oattn16);
  // QL = o_attn @ Wcomb^T + biasq ;  KL = aft @ k_w^T + k_b
  k_gemm<<<dim3(98, 8), 256, 0, stream>>>(oattn16, wcomb16, QL16, biasq, 6272, 512, 1);
  k_gemm<<<dim3(98, 8), 256, 0, stream>>>(aft16, kw16, KL16, k_b, 6272, 512, 1);
  // logits reductions
  k_init<<<784, 256, 0, stream>>>(t2v, colmax);
  k_logits<<<dim3(32, 32, 4), 256, 0, stream>>>(QL16, KL16, t2v, colmax);
  // final loss
  k_final<<<1, 256, 0, stream>>>(t2v, colmax, logit_scale, out);
}

// Round 3
// 476.035 us; speedup vs baseline: 1.3660x; 1.0566x over previous
//
#include <hip/hip_runtime.h>

// B=32, LV=196, LT=40, D=512, H=8, DH=64

typedef unsigned int u32;
typedef unsigned short u16;
typedef __attribute__((ext_vector_type(8))) short bf16x8;
typedef __attribute__((ext_vector_type(4))) float f32x4;

#define DEV __device__ __forceinline__

DEV u16 f2bf(float f) {
  u32 u = __builtin_bit_cast(u32, f);
  u = (u + 0x7FFFu + ((u >> 16) & 1u)) >> 16;
  return (u16)u;
}
DEV float bf2f(u16 h) { u32 u = ((u32)h) << 16; return __builtin_bit_cast(float, u); }
// monotonic float<->u32 encoding for atomicMax on floats (enc(x)>enc(y) iff x>y)
DEV u32 encf(float f) { u32 u = __builtin_bit_cast(u32, f); return (u & 0x80000000u) ? ~u : (u | 0x80000000u); }
DEV float decf(u32 e) { u32 u = (e & 0x80000000u) ? (e & 0x7FFFFFFFu) : ~e; return __builtin_bit_cast(float, u); }

// ---------------- cast kernels ----------------
__global__ void k_cast(const float* __restrict__ in, u16* __restrict__ out, int n8) {
  int i = blockIdx.x * blockDim.x + threadIdx.x;
  if (i >= n8) return;
  const float4* p = (const float4*)in + (size_t)i * 2;
  float4 a = p[0], b = p[1];
  u16 t[8] = {f2bf(a.x), f2bf(a.y), f2bf(a.z), f2bf(a.w),
              f2bf(b.x), f2bf(b.y), f2bf(b.z), f2bf(b.w)};
  *(uint4*)(out + (size_t)i * 8) = *(uint4*)t;
}

// conv1_w is (512 out, 1024 in); image half = cols [0,512) -> W1a (512x512) bf16
__global__ void k_cast_conv1a(const float* __restrict__ w, u16* __restrict__ out) {
  int i = blockIdx.x * blockDim.x + threadIdx.x; // 32768 threads
  int o = i >> 6, c0 = (i & 63) * 8;
  const float* p = w + (size_t)o * 1024 + c0;
  u16 t[8];
#pragma unroll
  for (int j = 0; j < 8; ++j) t[j] = f2bf(p[j]);
  *(uint4*)(out + (size_t)o * 512 + c0) = *(uint4*)t;
}

// out[r*512+c] = bf16(in[c*512+r])  (512x512)
__global__ __launch_bounds__(256) void k_transpose_cast(const float* __restrict__ in, u16* __restrict__ out) {
  __shared__ float t[32][33];
  int bx = blockIdx.x, by = blockIdx.y;
  int tx = threadIdx.x & 31, ty = threadIdx.x >> 5;
  for (int i = ty; i < 32; i += 8) t[i][tx] = in[(size_t)(by * 32 + i) * 512 + bx * 32 + tx];
  __syncthreads();
  for (int i = ty; i < 32; i += 8) out[(size_t)(bx * 32 + i) * 512 + by * 32 + tx] = f2bf(t[tx][i]);
}

// ---------------- small precompute kernels ----------------
__global__ __launch_bounds__(256) void k_sentbias(const float* __restrict__ sent, const float* __restrict__ masks,
                                                  const float* __restrict__ conv1_w, const float* __restrict__ conv1_b,
                                                  float* __restrict__ biasb) {
  int b = blockIdx.x;
  __shared__ float sm[512];
  int tid = threadIdx.x;
  for (int d = tid; d < 512; d += 256) {
    float s = 0.f;
#pragma unroll 8
    for (int t = 0; t < 40; ++t) s += sent[(size_t)b * 40 * 512 + (size_t)t * 512 + d] * masks[b * 40 + t];
    sm[d] = s * (1.0f / 40.0f);
  }
  __syncthreads();
  for (int o = tid; o < 512; o += 256) {
    const float* wr = conv1_w + (size_t)o * 1024 + 512;
    float acc = conv1_b[o];
#pragma unroll 8
    for (int c = 0; c < 512; ++c) acc += sm[c] * wr[c];
    biasb[b * 512 + o] = acc;
  }
}

__global__ void k_biasq(const float* __restrict__ q_w, const float* __restrict__ conv2_b,
                        const float* __restrict__ q_b, float* __restrict__ biasq) {
  int j = blockIdx.x * blockDim.x + threadIdx.x;
  if (j >= 512) return;
  const float* wr = q_w + (size_t)j * 512;
  float acc = q_b[j];
#pragma unroll 8
  for (int d = 0; d < 512; ++d) acc += wr[d] * conv2_b[d];
  biasq[j] = acc;
}

// ---------------- generic bf16 MFMA GEMM: C = X(MxK) @ W(NxK)^T, K=512 ----------------
// biasMode: 0 none, 1 per-col bias[col], 2 per-batch-row bias[(row/196)*512+col]
__global__ __launch_bounds__(256) void k_gemm(const u16* __restrict__ X, const u16* __restrict__ W,
                                              u16* __restrict__ out, const float* __restrict__ bias,
                                              int M, int N, int biasMode) {
  const int K = 512;
  __shared__ u16 Xl[64 * 72];
  __shared__ u16 Wl[64 * 72];
  int tid = threadIdx.x;
  int tileM = blockIdx.x * 64, tileN = blockIdx.y * 64;
  int wave = tid >> 6, lane = tid & 63, quad = lane >> 4, l15 = lane & 15;
  f32x4 z = {0.f, 0.f, 0.f, 0.f};
  f32x4 acc[4] = {z, z, z, z};
  int srow = tid >> 2;
  int sk = (tid & 3) * 16;
  const u16* gx = X + (size_t)(tileM + srow) * K + sk;
  const u16* gw = W + (size_t)(tileN + srow) * K + sk;
  u16* lx = &Xl[srow * 72 + sk];
  u16* lw = &Wl[srow * 72 + sk];
  for (int kc = 0; kc < K; kc += 64) {
    uint4 x0 = *(const uint4*)(gx + kc);
    uint4 x1 = *(const uint4*)(gx + kc + 8);
    uint4 w0 = *(const uint4*)(gw + kc);
    uint4 w1 = *(const uint4*)(gw + kc + 8);
    __syncthreads();
    *(uint4*)lx = x0; *(uint4*)(lx + 8) = x1;
    *(uint4*)lw = w0; *(uint4*)(lw + 8) = w1;
    __syncthreads();
    const u16* ax = &Xl[(wave * 16 + l15) * 72 + quad * 8];
#pragma unroll
    for (int kk = 0; kk < 64; kk += 32) {
      bf16x8 af = *(const bf16x8*)(ax + kk);
#pragma unroll
      for (int nt = 0; nt < 4; ++nt) {
        bf16x8 bfr = *(const bf16x8*)&Wl[(nt * 16 + l15) * 72 + kk + quad * 8];
        acc[nt] = __builtin_amdgcn_mfma_f32_16x16x32_bf16(af, bfr, acc[nt], 0, 0, 0);
      }
    }
  }
  int row0 = tileM + wave * 16 + quad * 4;
#pragma unroll
  for (int nt = 0; nt < 4; ++nt) {
    int col = tileN + nt * 16 + l15;
    float bv = (biasMode == 1) ? bias[col] : 0.0f;
#pragma unroll
    for (int r = 0; r < 4; ++r) {
      int row = row0 + r;
      float v = acc[nt][r] + bv;
      if (biasMode == 2) v += bias[(row / 196) * 512 + col];
      out[(size_t)row * N + col] = f2bf(v);
    }
  }
}

// ---------------- MFMA attention: one block (4 waves) per (b,h) ----------------
__global__ __launch_bounds__(256, 1) void k_attn2(const u16* __restrict__ qkv, u16* __restrict__ o_out) {
  const int b = blockIdx.x >> 3, h = blockIdx.x & 7;
  __shared__ u16 Ks[208 * 72];
  __shared__ u16 Vt[64 * 232];
  __shared__ u16 Ps[4][16 * 232];
  const int tid = threadIdx.x;
  const int wave = tid >> 6, lane = tid & 63, quad = lane >> 4, l15 = lane & 15;
  const size_t base = (size_t)b * 196 * 1536 + (size_t)h * 64;

  for (int i = tid; i < 64 * 232 / 4; i += 256) ((unsigned long long*)Vt)[i] = 0ULL;
  for (int i = tid; i < 4 * 16 * 24; i += 256) {
    int w = i / 384, rem = i - w * 384;
    int r = rem / 24, c = rem - r * 24;
    Ps[w][r * 232 + 208 + c] = 0;
  }
  __syncthreads();

  for (int idx = tid; idx < 208 * 8; idx += 256) {
    int r = idx >> 3, c = (idx & 7) * 8;
    uint4 v = {0, 0, 0, 0};
    if (r < 196) v = *(const uint4*)&qkv[base + 512 + (size_t)r * 1536 + c];
    *(uint4*)&Ks[r * 72 + c] = v;
  }
  for (int idx = tid; idx < 196 * 8; idx += 256) {
    int p = idx >> 3, f0 = (idx & 7) * 8;
    uint4 v = *(const uint4*)&qkv[base + 1024 + (size_t)p * 1536 + f0];
    u16 t[8]; *(uint4*)t = v;
#pragma unroll
    for (int j = 0; j < 8; ++j) Vt[(f0 + j) * 232 + p] = t[j];
  }
  bf16x8 qz = {0, 0, 0, 0, 0, 0, 0, 0};
  bf16x8 qf[4][2];
#pragma unroll
  for (int i = 0; i < 4; ++i) {
    int s = wave + i * 4;
    int row = s * 16 + l15;
#pragma unroll
    for (int c = 0; c < 2; ++c) {
      bf16x8 v = qz;
      if (s < 13 && row < 196)
        v = *(const bf16x8*)&qkv[base + (size_t)row * 1536 + c * 32 + quad * 8];
      qf[i][c] = v;
    }
  }
  __syncthreads();

  const f32x4 z = {0.f, 0.f, 0.f, 0.f};
  for (int i = 0; i < 4; ++i) {
    int s = wave + i * 4;
    if (s >= 13) break;
    f32x4 acc[13];
#pragma unroll
    for (int nt = 0; nt < 13; ++nt) acc[nt] = z;
#pragma unroll
    for (int c = 0; c < 2; ++c) {
      bf16x8 a = qf[i][c];
#pragma unroll
      for (int nt = 0; nt < 13; ++nt) {
        bf16x8 bfr = *(const bf16x8*)&Ks[(nt * 16 + l15) * 72 + c * 32 + quad * 8];
        acc[nt] = __builtin_amdgcn_mfma_f32_16x16x32_bf16(a, bfr, acc[nt], 0, 0, 0);
      }
    }
#pragma unroll
    for (int r = 0; r < 4; ++r) {
      float m = -3e38f;
#pragma unroll
      for (int nt = 0; nt < 13; ++nt) {
        float sv = acc[nt][r] * 0.125f;
        acc[nt][r] = sv;
        if (nt < 12 || l15 < 4) m = fmaxf(m, sv);
      }
#pragma unroll
      for (int off = 1; off < 16; off <<= 1) m = fmaxf(m, __shfl_xor(m, off));
      float ssum = 0.f;
#pragma unroll
      for (int nt = 0; nt < 13; ++nt) {
        float p = (nt < 12 || l15 < 4) ? __expf(acc[nt][r] - m) : 0.f;
        acc[nt][r] = p;
        ssum += p;
      }
#pragma unroll
      for (int off = 1; off < 16; off <<= 1) ssum += __shfl_xor(ssum, off);
      float is = 1.0f / ssum;
      int row = quad * 4 + r;
#pragma unroll
      for (int nt = 0; nt < 13; ++nt) {
        float v = acc[nt][r] * is;
        float vx = __shfl_xor(v, 1);
        if ((l15 & 1) == 0) {
          u32 pk = (u32)f2bf(v) | ((u32)f2bf(vx) << 16);
          *(u32*)&Ps[wave][row * 232 + nt * 16 + l15] = pk;
        }
      }
    }
    f32x4 oacc[4] = {z, z, z, z};
#pragma unroll
    for (int kc = 0; kc < 7; ++kc) {
      bf16x8 a = *(const bf16x8*)&Ps[wave][l15 * 232 + kc * 32 + quad * 8];
#pragma unroll
      for (int nt = 0; nt < 4; ++nt) {
        bf16x8 bfr = *(const bf16x8*)&Vt[(nt * 16 + l15) * 232 + kc * 32 + quad * 8];
        oacc[nt] = __builtin_amdgcn_mfma_f32_16x16x32_bf16(a, bfr, oacc[nt], 0, 0, 0);
      }
    }
#pragma unroll
    for (int nt = 0; nt < 4; ++nt) {
#pragma unroll
      for (int r = 0; r < 4; ++r) {
        int row = s * 16 + quad * 4 + r;
        if (row < 196)
          o_out[((size_t)b * 196 + row) * 512 + h * 64 + nt * 16 + l15] = f2bf(oacc[nt][r]);
      }
    }
  }
}

// ---------------- init for reduction buffers (rowmax+colmax contiguous) ----------------
__global__ void k_init(uint4* __restrict__ maxbuf) {
  int i = blockIdx.x * blockDim.x + threadIdx.x; // 392*256 = 100352 = 2*200704/4
  maxbuf[i] = (uint4){0u, 0u, 0u, 0u};
}

// ---------------- logits: C = QL(6272x512) @ KL(6272x512)^T, fused row/col max ----------------
// grid (49,32): 128 global rows x 208 cols (= one b's 196, padded). 4 waves,
// each wave owns row-strips {w, w+4}: acc[2][13] -> 15 ds_reads / 26 MFMAs.
// Rows may span an a-boundary (at most one per block): rowmax atomics are
// per-row keyed; colmax LDS reduce is segmented into <=2 a-buckets.
__global__ __launch_bounds__(256) void k_logits2(const u16* __restrict__ QL, const u16* __restrict__ KL,
                                                 u32* __restrict__ rowmax, u32* __restrict__ colmax) {
  const int row0 = blockIdx.x * 128;
  const int b = blockIdx.y;
  __shared__ u16 Ql[128 * 72];        // 18,432 B
  __shared__ u16 Kl[208 * 72];        // 29,952 B
  __shared__ float colred[2][4 * 208];// 6,656 B
  const int tid = threadIdx.x;
  const int wave = tid >> 6, lane = tid & 63, quad = lane >> 4, l15 = lane & 15;
  const int a0 = row0 / 196;
  const int lsplit = (a0 + 1) * 196 - row0; // local row where a increments (>=128 => single segment)
  const f32x4 z = {0.f, 0.f, 0.f, 0.f};
  f32x4 acc[2][13];
#pragma unroll
  for (int s = 0; s < 2; ++s)
#pragma unroll
    for (int nt = 0; nt < 13; ++nt) acc[s][nt] = z;
  const u16* qbase = QL + (size_t)row0 * 512;
  const u16* kbase = KL + (size_t)b * 196 * 512;

  for (int kc = 0; kc < 512; kc += 64) {
    uint4 qreg[4];
#pragma unroll
    for (int i = 0; i < 4; ++i) {
      int idx = tid + i * 256, r = idx >> 3, c = (idx & 7) * 8;
      qreg[i] = *(const uint4*)(qbase + (size_t)r * 512 + kc + c);
    }
    uint4 kreg[7];
#pragma unroll
    for (int i = 0; i < 7; ++i) {
      int idx = tid + i * 256, r = idx >> 3, c = (idx & 7) * 8;
      uint4 v = {0, 0, 0, 0};
      if (idx < 1664 && r < 196) v = *(const uint4*)(kbase + (size_t)r * 512 + kc + c);
      kreg[i] = v;
    }
    __syncthreads();
#pragma unroll
    for (int i = 0; i < 4; ++i) {
      int idx = tid + i * 256, r = idx >> 3, c = (idx & 7) * 8;
      *(uint4*)&Ql[r * 72 + c] = qreg[i];
    }
#pragma unroll
    for (int i = 0; i < 7; ++i) {
      int idx = tid + i * 256;
      if (idx < 1664) {
        int r = idx >> 3, c = (idx & 7) * 8;
        *(uint4*)&Kl[r * 72 + c] = kreg[i];
      }
    }
    __syncthreads();
#pragma unroll
    for (int kk = 0; kk < 64; kk += 32) {
      bf16x8 af0 = *(const bf16x8*)&Ql[(wave * 16 + l15) * 72 + kk + quad * 8];
      bf16x8 af1 = *(const bf16x8*)&Ql[((wave + 4) * 16 + l15) * 72 + kk + quad * 8];
#pragma unroll
      for (int nt = 0; nt < 13; ++nt) {
        bf16x8 bfr = *(const bf16x8*)&Kl[(nt * 16 + l15) * 72 + kk + quad * 8];
        acc[0][nt] = __builtin_amdgcn_mfma_f32_16x16x32_bf16(af0, bfr, acc[0][nt], 0, 0, 0);
        acc[1][nt] = __builtin_amdgcn_mfma_f32_16x16x32_bf16(af1, bfr, acc[1][nt], 0, 0, 0);
      }
    }
  }
  // ---- rowmax: complete within block (all 196 cols of b present) ----
#pragma unroll
  for (int s = 0; s < 2; ++s) {
#pragma unroll
    for (int r = 0; r < 4; ++r) {
      float m = -3e38f;
#pragma unroll
      for (int nt = 0; nt < 13; ++nt)
        if (nt < 12 || l15 < 4) m = fmaxf(m, acc[s][nt][r]);
#pragma unroll
      for (int off = 8; off > 0; off >>= 1) m = fmaxf(m, __shfl_xor(m, off, 16));
      if (l15 == 0) {
        int lr = (wave + s * 4) * 16 + quad * 4 + r;
        int aa = a0, ll = row0 - a0 * 196 + lr;
        if (ll >= 196) { aa += 1; ll -= 196; }
        atomicMax(&rowmax[((size_t)aa * 32 + b) * 196 + ll], encf(m));
      }
    }
  }
  // ---- colmax: segment rows by a before cross-quad shuffles ----
#pragma unroll
  for (int nt = 0; nt < 13; ++nt) {
    float cm0 = -3e38f, cm1 = -3e38f;
#pragma unroll
    for (int s = 0; s < 2; ++s)
#pragma unroll
      for (int r = 0; r < 4; ++r) {
        int lr = (wave + s * 4) * 16 + quad * 4 + r;
        float v = acc[s][nt][r];
        if (lr < lsplit) cm0 = fmaxf(cm0, v); else cm1 = fmaxf(cm1, v);
      }
    cm0 = fmaxf(cm0, __shfl_xor(cm0, 16)); cm0 = fmaxf(cm0, __shfl_xor(cm0, 32));
    cm1 = fmaxf(cm1, __shfl_xor(cm1, 16)); cm1 = fmaxf(cm1, __shfl_xor(cm1, 32));
    if (quad == 0) {
      colred[0][wave * 208 + nt * 16 + l15] = cm0;
      colred[1][wave * 208 + nt * 16 + l15] = cm1;
    }
  }
  __syncthreads();
  for (int c = tid; c < 196; c += 256) {
    float m0 = fmaxf(fmaxf(colred[0][c], colred[0][208 + c]), fmaxf(colred[0][416 + c], colred[0][624 + c]));
    atomicMax(&colmax[((size_t)a0 * 32 + b) * 196 + c], encf(m0));
    if (lsplit < 128) {
      float m1 = fmaxf(fmaxf(colred[1][c], colred[1][208 + c]), fmaxf(colred[1][416 + c], colred[1][624 + c]));
      atomicMax(&colmax[((size_t)(a0 + 1) * 32 + b) * 196 + c], encf(m1));
    }
  }
}

// ---------------- final: S matrix + symmetric cross-entropy ----------------
__global__ __launch_bounds__(1024) void k_final(const u32* __restrict__ maxbuf,
                                                const float* __restrict__ logit_scale, float* __restrict__ out) {
  __shared__ float S[1024];
  __shared__ float terms[64];
  int tid = threadIdx.x; // == pair
  float sc = 0.5f * __expf(logit_scale[0]);
  const uint4* rp = (const uint4*)(maxbuf + (size_t)tid * 196);
  const uint4* cp = (const uint4*)(maxbuf + 200704 + (size_t)tid * 196);
  float s = 0.f;
#pragma unroll 7
  for (int i = 0; i < 49; ++i) {
    uint4 v = rp[i]; s += decf(v.x) + decf(v.y) + decf(v.z) + decf(v.w);
    uint4 w = cp[i]; s += decf(w.x) + decf(w.y) + decf(w.z) + decf(w.w);
  }
  S[tid] = sc * s * (1.0f / 196.0f);
  __syncthreads();
  if (tid < 64) {
    int aa = tid & 31;
    bool rowMode = tid < 32;
    float mx = -3e38f;
    for (int j = 0; j < 32; ++j) {
      float v = rowMode ? S[aa * 32 + j] : S[j * 32 + aa];
      mx = fmaxf(mx, v);
    }
    float se = 0.f;
    for (int j = 0; j < 32; ++j) {
      float v = rowMode ? S[aa * 32 + j] : S[j * 32 + aa];
      se += __expf(v - mx);
    }
    terms[tid] = S[aa * 33] - (mx + logf(se));
  }
  __syncthreads();
  if (tid == 0) {
    float s2 = 0.f;
    for (int i = 0; i < 64; ++i) s2 += terms[i];
    out[0] = -s2 * (1.0f / 64.0f);
  }
}

// ---------------- host ----------------
extern "C" void kernel_launch(void* const* d_in, const int* in_sizes, int n_in,
                              void* d_out, int out_size, void* d_ws, size_t ws_size,
                              hipStream_t stream) {
  const float* bef       = (const float*)d_in[0];
  const float* sent      = (const float*)d_in[1];
  const float* aft       = (const float*)d_in[2];
  const float* masks     = (const float*)d_in[3];
  const float* conv1_w   = (const float*)d_in[4];
  const float* conv1_b   = (const float*)d_in[5];
  const float* in_proj_w = (const float*)d_in[6];
  const float* out_proj_w= (const float*)d_in[7];
  const float* conv2_w   = (const float*)d_in[8];
  const float* conv2_b   = (const float*)d_in[9];
  const float* q_w       = (const float*)d_in[10];
  const float* q_b       = (const float*)d_in[11];
  const float* k_w       = (const float*)d_in[12];
  const float* k_b       = (const float*)d_in[13];
  const float* logit_scale = (const float*)d_in[14];
  float* out = (float*)d_out;

  char* ws = (char*)d_ws;
  size_t off = 0;
  auto alloc = [&](size_t bytes) -> char* {
    char* p = ws + off;
    off += (bytes + 255) & ~(size_t)255;
    return p;
  };
  const size_t MROWS = 32 * 196; // 6272
  u16* bef16    = (u16*)alloc(MROWS * 512 * 2);
  u16* aft16    = (u16*)alloc(MROWS * 512 * 2);
  u16* w1a16    = (u16*)alloc(512 * 512 * 2);
  u16* inproj16 = (u16*)alloc(1536 * 512 * 2);
  u16* kw16     = (u16*)alloc(512 * 512 * 2);
  u16* qw16     = (u16*)alloc(512 * 512 * 2);
  u16* wcT16    = (u16*)alloc(512 * 512 * 2);
  u16* woT16    = (u16*)alloc(512 * 512 * 2);
  u16* wt16     = (u16*)alloc(512 * 512 * 2);
  u16* wcomb16  = (u16*)alloc(512 * 512 * 2);
  float* biasb  = (float*)alloc(32 * 512 * 4);
  float* biasq  = (float*)alloc(512 * 4);
  u16* v116     = (u16*)alloc(MROWS * 512 * 2);
  u16* qkv16    = (u16*)alloc(MROWS * 1536 * 2);
  u16* oattn16  = (u16*)alloc(MROWS * 512 * 2);
  u16* QL16     = (u16*)alloc(MROWS * 512 * 2);
  u16* KL16     = (u16*)alloc(MROWS * 512 * 2);
  u32* maxbuf   = (u32*)alloc(2 * 32 * 32 * 196 * 4); // rowmax | colmax
  u32* rowmax   = maxbuf;
  u32* colmax   = maxbuf + 32 * 32 * 196;

  // casts
  k_cast<<<1568, 256, 0, stream>>>(bef, bef16, 401408);
  k_cast<<<1568, 256, 0, stream>>>(aft, aft16, 401408);
  k_cast<<<384, 256, 0, stream>>>(in_proj_w, inproj16, 98304);
  k_cast<<<128, 256, 0, stream>>>(k_w, kw16, 32768);
  k_cast<<<128, 256, 0, stream>>>(q_w, qw16, 32768);
  k_cast_conv1a<<<128, 256, 0, stream>>>(conv1_w, w1a16);
  k_transpose_cast<<<dim3(16, 16), 256, 0, stream>>>(conv2_w, wcT16);
  k_transpose_cast<<<dim3(16, 16), 256, 0, stream>>>(out_proj_w, woT16);
  // small precomputes
  k_sentbias<<<32, 256, 0, stream>>>(sent, masks, conv1_w, conv1_b, biasb);
  k_biasq<<<2, 256, 0, stream>>>(q_w, conv2_b, q_b, biasq);
  // weight composition: Wcomb = Wq @ Wc @ Wo
  k_gemm<<<dim3(8, 8), 256, 0, stream>>>(qw16, wcT16, wt16, nullptr, 512, 512, 0);
  k_gemm<<<dim3(8, 8), 256, 0, stream>>>(wt16, woT16, wcomb16, nullptr, 512, 512, 0);
  // v1 = bef @ W1a^T + biasb[b]
  k_gemm<<<dim3(98, 8), 256, 0, stream>>>(bef16, w1a16, v116, biasb, 6272, 512, 2);
  // qkv = v1 @ in_proj^T
  k_gemm<<<dim3(98, 24), 256, 0, stream>>>(v116, inproj16, qkv16, nullptr, 6272, 1536, 0);
  // attention (MFMA)
  k_attn2<<<256, 256, 0, stream>>>(qkv16, oattn16);
  // QL = o_attn @ Wcomb^T + biasq ;  KL = aft @ k_w^T + k_b
  k_gemm<<<dim3(98, 8), 256, 0, stream>>>(oattn16, wcomb16, QL16, biasq, 6272, 512, 1);
  k_gemm<<<dim3(98, 8), 256, 0, stream>>>(aft16, kw16, KL16, k_b, 6272, 512, 1);
  // logits reductions
  k_init<<<392, 256, 0, stream>>>((uint4*)maxbuf);
  k_logits2<<<dim3(49, 32), 256, 0, stream>>>(QL16, KL16, rowmax, colmax);
  // final loss
  k_final<<<1, 1024, 0, stream>>>(maxbuf, logit_scale, out);
}